// Round 1
// baseline (225.716 us; speedup 1.0000x reference)
//
#include <hip/hip_runtime.h>
#include <hip/hip_bf16.h>
#include <stdint.h>

typedef unsigned short u16;
typedef __attribute__((ext_vector_type(8))) short short8;
typedef __attribute__((ext_vector_type(4))) float f32x4;
typedef __attribute__((ext_vector_type(4))) float f32x4v;
typedef __attribute__((ext_vector_type(4))) unsigned int u32x4;
typedef __attribute__((ext_vector_type(4))) unsigned short u16x4;

#define MFMA16(a, b, c) __builtin_amdgcn_mfma_f32_16x16x32_bf16((a), (b), (c), 0, 0, 0)

__device__ __forceinline__ u16 f2bf(float f) {
    union { float f; uint32_t u; } v; v.f = f;
    return (u16)((v.u + 0x7FFFu + ((v.u >> 16) & 1u)) >> 16);
}

// ---------------- convert kernels ----------------

__global__ __launch_bounds__(256) void k_cvt_x(const float* __restrict__ in,
                                               u16* __restrict__ out, int n) {
    int i = (blockIdx.x * 256 + threadIdx.x) * 4;
    if (i >= n) return;
    f32x4 v = *(const f32x4*)(in + i);
    u16x4 o;
    o[0] = f2bf(v[0]); o[1] = f2bf(v[1]); o[2] = f2bf(v[2]); o[3] = f2bf(v[3]);
    *(u16x4*)(out + i) = o;
}

// out[n*K + k] = bf16(in[k*N + n])   (transpose + convert)
__global__ __launch_bounds__(256) void k_cvt_T(const float* __restrict__ in,
                                               u16* __restrict__ out, int K, int N) {
    int i = blockIdx.x * 256 + threadIdx.x;
    if (i >= K * N) return;
    int n = i % N, k = i / N;
    out[(size_t)n * K + k] = f2bf(in[i]);
}

// ---------------- GEMM1: qkv = x @ w_qkv + b, scatter to Q/K/V [BH][T][D] bf16 ----------------

__global__ __launch_bounds__(256) void k_gemm_qkv(const u16* __restrict__ A,   // [8192][768]
                                                  const u16* __restrict__ BT,  // [2304][768]
                                                  const float* __restrict__ bias, // [2304]
                                                  u16* __restrict__ Qb,
                                                  u16* __restrict__ Kb,
                                                  u16* __restrict__ Vb) {
    const int K = 768;
    __shared__ __align__(16) u16 As[128 * 32];
    __shared__ __align__(16) u16 Bs[128 * 32];
    const int tid = threadIdx.x;
    const int wave = tid >> 6, lane = tid & 63;
    const int wr = wave >> 1, wc = wave & 1;
    const int g = lane >> 4, lr = lane & 15;
    const int m0 = blockIdx.y * 128, n0 = blockIdx.x * 128;

    f32x4 acc[4][4];
#pragma unroll
    for (int i = 0; i < 4; ++i)
#pragma unroll
        for (int j = 0; j < 4; ++j) acc[i][j] = (f32x4){0.f, 0.f, 0.f, 0.f};

    for (int k0 = 0; k0 < K; k0 += 32) {
        __syncthreads();
#pragma unroll
        for (int it = 0; it < 2; ++it) {
            int c = tid + it * 256;
            int m = c >> 2, k8 = (c & 3) << 3;
            *(u32x4*)&As[m * 32 + k8] = *(const u32x4*)&A[(size_t)(m0 + m) * K + k0 + k8];
            *(u32x4*)&Bs[m * 32 + k8] = *(const u32x4*)&BT[(size_t)(n0 + m) * K + k0 + k8];
        }
        __syncthreads();
        short8 af[4], bf[4];
#pragma unroll
        for (int i = 0; i < 4; ++i)
            af[i] = *(const short8*)&As[(64 * wr + 16 * i + lr) * 32 + 8 * g];
#pragma unroll
        for (int j = 0; j < 4; ++j)
            bf[j] = *(const short8*)&Bs[(64 * wc + 16 * j + lr) * 32 + 8 * g];
#pragma unroll
        for (int i = 0; i < 4; ++i)
#pragma unroll
            for (int j = 0; j < 4; ++j)
                acc[i][j] = MFMA16(af[i], bf[j], acc[i][j]);
    }

#pragma unroll
    for (int i = 0; i < 4; ++i) {
        int row = m0 + 64 * wr + 16 * i + 4 * g;
#pragma unroll
        for (int j = 0; j < 4; ++j) {
            int col = n0 + 64 * wc + 16 * j + lr;
            int part = col / 768;
            int jj = col - part * 768;
            int h = jj / 96, d = jj - h * 96;
            u16* dst = part == 0 ? Qb : (part == 1 ? Kb : Vb);
            float b = bias[col];
#pragma unroll
            for (int r = 0; r < 4; ++r) {
                int rw = row + r;
                int t = rw & 1023, bb = rw >> 10;
                dst[((size_t)(bb * 8 + h) * 1024 + t) * 96 + d] = f2bf(acc[i][j][r] + b);
            }
        }
    }
}

// ---------------- flash attention: per (q-tile, bh) ----------------

__global__ __launch_bounds__(256) void k_attn(const u16* __restrict__ Qb,
                                              const u16* __restrict__ Kb,
                                              const u16* __restrict__ Vb,
                                              u16* __restrict__ Yatt) {
    __shared__ __align__(16) u16 Ks[64 * 104];   // K tile [64 rows][96 d] pad 104
    __shared__ __align__(16) u16 Vt[96 * 72];    // V^T tile [96 d][64 rows] pad 72
    __shared__ __align__(16) u16 Ps[4][16 * 72]; // per-wave P tile [16][64] pad 72

    const int tid = threadIdx.x;
    const int wave = tid >> 6, lane = tid & 63;
    const int g = lane >> 4, lr = lane & 15;
    const int qt = blockIdx.x, bh = blockIdx.y;
    const int q0 = qt * 64;
    const size_t base = (size_t)bh * 1024 * 96;
    const float scale = 0.10206207261596577f; // 1/sqrt(96)

    // Q fragments in registers: rows q0+16*wave+lr, d = 32kk+8g..+7
    short8 qf[3];
    {
        int qrow = q0 + 16 * wave + lr;
#pragma unroll
        for (int kk = 0; kk < 3; ++kk)
            qf[kk] = *(const short8*)&Qb[base + (size_t)qrow * 96 + 32 * kk + 8 * g];
    }

    float m_r[4], l_r[4];
    f32x4 o[6];
#pragma unroll
    for (int r = 0; r < 4; ++r) { m_r[r] = -3e38f; l_r[r] = 0.f; }
#pragma unroll
    for (int c = 0; c < 6; ++c) o[c] = (f32x4){0.f, 0.f, 0.f, 0.f};

    for (int kt = 0; kt <= qt; ++kt) {
        __syncthreads();
        // stage K tile: Ks[r][d]
#pragma unroll
        for (int it = 0; it < 3; ++it) {
            int c = tid + it * 256;            // 0..767 chunks of 8
            int r = c / 12, k8 = (c % 12) * 8;
            *(u32x4*)&Ks[r * 104 + k8] =
                *(const u32x4*)&Kb[base + (size_t)(kt * 64 + r) * 96 + k8];
        }
        // stage V tile transposed: Vt[d][r] = V[kt*64+r][d]
#pragma unroll
        for (int it = 0; it < 3; ++it) {
            int c = tid + it * 256;            // 0..767
            int r = c & 63, d8 = (c >> 6) * 8;
            u32x4 vv = *(const u32x4*)&Vb[base + (size_t)(kt * 64 + r) * 96 + d8];
            const u16* vs = (const u16*)&vv;
#pragma unroll
            for (int p = 0; p < 8; ++p)
                Vt[(d8 + p) * 72 + r] = vs[p];
        }
        __syncthreads();

        // S = Q @ K^T per wave: 16 rows x 64 cols
        f32x4 s[4];
#pragma unroll
        for (int j = 0; j < 4; ++j) {
            s[j] = (f32x4){0.f, 0.f, 0.f, 0.f};
#pragma unroll
            for (int kk = 0; kk < 3; ++kk) {
                short8 kf = *(const short8*)&Ks[(16 * j + lr) * 104 + 32 * kk + 8 * g];
                s[j] = MFMA16(qf[kk], kf, s[j]);
            }
        }
#pragma unroll
        for (int j = 0; j < 4; ++j)
#pragma unroll
            for (int r = 0; r < 4; ++r) s[j][r] *= scale;

        if (kt == qt) { // diagonal tile: mask local col > local row
#pragma unroll
            for (int j = 0; j < 4; ++j) {
                int lc = 16 * j + lr;
#pragma unroll
                for (int r = 0; r < 4; ++r) {
                    int lrow = 16 * wave + 4 * g + r;
                    if (lc > lrow) s[j][r] = -3e38f;
                }
            }
        }

        // online softmax (rows 4g+r, shared by the 16 lanes of each group)
        float alpha[4], rsum[4];
#pragma unroll
        for (int r = 0; r < 4; ++r) {
            float mx = fmaxf(fmaxf(s[0][r], s[1][r]), fmaxf(s[2][r], s[3][r]));
#pragma unroll
            for (int off = 1; off < 16; off <<= 1)
                mx = fmaxf(mx, __shfl_xor(mx, off, 64));
            float mnew = fmaxf(m_r[r], mx);
            alpha[r] = __expf(m_r[r] - mnew);
            m_r[r] = mnew;
            rsum[r] = 0.f;
        }
#pragma unroll
        for (int j = 0; j < 4; ++j)
#pragma unroll
            for (int r = 0; r < 4; ++r) {
                float p = __expf(s[j][r] - m_r[r]);
                rsum[r] += p;
                Ps[wave][(4 * g + r) * 72 + 16 * j + lr] = f2bf(p);
            }
#pragma unroll
        for (int r = 0; r < 4; ++r) {
#pragma unroll
            for (int off = 1; off < 16; off <<= 1)
                rsum[r] += __shfl_xor(rsum[r], off, 64);
            l_r[r] = l_r[r] * alpha[r] + rsum[r];
        }
#pragma unroll
        for (int c = 0; c < 6; ++c)
#pragma unroll
            for (int r = 0; r < 4; ++r) o[c][r] *= alpha[r];

        __syncthreads();

        // PV: o += P @ V  (A = Ps rows, B = Vt cols)
        short8 pf[2];
#pragma unroll
        for (int kk = 0; kk < 2; ++kk)
            pf[kk] = *(const short8*)&Ps[wave][lr * 72 + 32 * kk + 8 * g];
#pragma unroll
        for (int c = 0; c < 6; ++c) {
#pragma unroll
            for (int kk = 0; kk < 2; ++kk) {
                short8 vf = *(const short8*)&Vt[(16 * c + lr) * 72 + 32 * kk + 8 * g];
                o[c] = MFMA16(pf[kk], vf, o[c]);
            }
        }
    }

    // epilogue: Yatt[b][t][h*96+d] bf16
    const int b = bh >> 3, h = bh & 7;
#pragma unroll
    for (int r = 0; r < 4; ++r) {
        int t = q0 + 16 * wave + 4 * g + r;
        float inv = 1.0f / l_r[r];
        size_t rowoff = ((size_t)b * 1024 + t) * 768 + h * 96;
#pragma unroll
        for (int c = 0; c < 6; ++c)
            Yatt[rowoff + 16 * c + lr] = f2bf(o[c][r] * inv);
    }
}

// ---------------- GEMM2: out = yatt @ w_proj + b_proj (fp32 out) ----------------

__global__ __launch_bounds__(256) void k_gemm_out(const u16* __restrict__ A,   // [8192][768]
                                                  const u16* __restrict__ BT,  // [768][768]
                                                  const float* __restrict__ bias, // [768]
                                                  float* __restrict__ out) {   // [8192][768]
    const int K = 768;
    __shared__ __align__(16) u16 As[128 * 32];
    __shared__ __align__(16) u16 Bs[128 * 32];
    const int tid = threadIdx.x;
    const int wave = tid >> 6, lane = tid & 63;
    const int wr = wave >> 1, wc = wave & 1;
    const int g = lane >> 4, lr = lane & 15;
    const int m0 = blockIdx.y * 128, n0 = blockIdx.x * 128;

    f32x4 acc[4][4];
#pragma unroll
    for (int i = 0; i < 4; ++i)
#pragma unroll
        for (int j = 0; j < 4; ++j) acc[i][j] = (f32x4){0.f, 0.f, 0.f, 0.f};

    for (int k0 = 0; k0 < K; k0 += 32) {
        __syncthreads();
#pragma unroll
        for (int it = 0; it < 2; ++it) {
            int c = tid + it * 256;
            int m = c >> 2, k8 = (c & 3) << 3;
            *(u32x4*)&As[m * 32 + k8] = *(const u32x4*)&A[(size_t)(m0 + m) * K + k0 + k8];
            *(u32x4*)&Bs[m * 32 + k8] = *(const u32x4*)&BT[(size_t)(n0 + m) * K + k0 + k8];
        }
        __syncthreads();
        short8 af[4], bf[4];
#pragma unroll
        for (int i = 0; i < 4; ++i)
            af[i] = *(const short8*)&As[(64 * wr + 16 * i + lr) * 32 + 8 * g];
#pragma unroll
        for (int j = 0; j < 4; ++j)
            bf[j] = *(const short8*)&Bs[(64 * wc + 16 * j + lr) * 32 + 8 * g];
#pragma unroll
        for (int i = 0; i < 4; ++i)
#pragma unroll
            for (int j = 0; j < 4; ++j)
                acc[i][j] = MFMA16(af[i], bf[j], acc[i][j]);
    }

#pragma unroll
    for (int i = 0; i < 4; ++i) {
        int row = m0 + 64 * wr + 16 * i + 4 * g;
#pragma unroll
        for (int j = 0; j < 4; ++j) {
            int col = n0 + 64 * wc + 16 * j + lr;
            float b = bias[col];
#pragma unroll
            for (int r = 0; r < 4; ++r)
                out[(size_t)(row + r) * 768 + col] = acc[i][j][r] + b;
        }
    }
}

// ---------------- launch ----------------

extern "C" void kernel_launch(void* const* d_in, const int* in_sizes, int n_in,
                              void* d_out, int out_size, void* d_ws, size_t ws_size,
                              hipStream_t stream) {
    const float* x      = (const float*)d_in[0];
    const float* w_qkv  = (const float*)d_in[1];
    const float* b_qkv  = (const float*)d_in[2];
    const float* w_proj = (const float*)d_in[3];
    const float* b_proj = (const float*)d_in[4];
    float* out = (float*)d_out;

    u16* xb    = (u16*)d_ws;            // 6291456
    u16* wqkvT = xb + 6291456;          // 1769472
    u16* wpT   = wqkvT + 1769472;       // 589824
    u16* Qb    = wpT + 589824;          // 6291456
    u16* Kb    = Qb + 6291456;          // 6291456
    u16* Vb    = Kb + 6291456;          // 6291456
    u16* Yatt  = Vb + 6291456;          // 6291456

    k_cvt_x<<<6144, 256, 0, stream>>>(x, xb, 6291456);
    k_cvt_T<<<6912, 256, 0, stream>>>(w_qkv, wqkvT, 768, 2304);
    k_cvt_T<<<2304, 256, 0, stream>>>(w_proj, wpT, 768, 768);
    k_gemm_qkv<<<dim3(18, 64), 256, 0, stream>>>(xb, wqkvT, b_qkv, Qb, Kb, Vb);
    k_attn<<<dim3(16, 64), 256, 0, stream>>>(Qb, Kb, Vb, Yatt);
    k_gemm_out<<<dim3(6, 64), 256, 0, stream>>>(Yatt, wpT, b_proj, out);
}

// Round 2
// 153.960 us; speedup vs baseline: 1.4661x; 1.4661x over previous
//
#include <hip/hip_runtime.h>
#include <hip/hip_bf16.h>
#include <stdint.h>

typedef unsigned short u16;
typedef unsigned int u32;
typedef __attribute__((ext_vector_type(8))) short short8;
typedef __attribute__((ext_vector_type(4))) float f32x4;
typedef __attribute__((ext_vector_type(4))) unsigned int u32x4;
typedef __attribute__((ext_vector_type(4))) unsigned short u16x4;

#define MFMA16(a, b, c) __builtin_amdgcn_mfma_f32_16x16x32_bf16((a), (b), (c), 0, 0, 0)

__device__ __forceinline__ u16 f2bf(float f) {
    union { float f; uint32_t u; } v; v.f = f;
    return (u16)((v.u + 0x7FFFu + ((v.u >> 16) & 1u)) >> 16);
}

// async global -> LDS, 16 bytes per lane
__device__ __forceinline__ void gl_lds16(const u16* g, u16* l) {
    __builtin_amdgcn_global_load_lds(
        (const __attribute__((address_space(1))) u32*)g,
        (__attribute__((address_space(3))) u32*)l,
        16, 0, 0);
}

// ---------------- convert kernels ----------------

__global__ __launch_bounds__(256) void k_cvt_x(const float* __restrict__ in,
                                               u16* __restrict__ out, int n) {
    int i = (blockIdx.x * 256 + threadIdx.x) * 4;
    if (i >= n) return;
    f32x4 v = *(const f32x4*)(in + i);
    u16x4 o;
    o[0] = f2bf(v[0]); o[1] = f2bf(v[1]); o[2] = f2bf(v[2]); o[3] = f2bf(v[3]);
    *(u16x4*)(out + i) = o;
}

// LDS-tiled transpose+convert: out[n*K+k] = bf16(in[k*N+n]); K,N multiples of 64
__global__ __launch_bounds__(256) void k_cvt_T(const float* __restrict__ in,
                                               u16* __restrict__ out, int K, int N) {
    __shared__ u16 t[64][72];
    const int kb = blockIdx.y * 64, nb = blockIdx.x * 64;
    const int tid = threadIdx.x;
    const int r = tid >> 4, c4 = (tid & 15) << 2;
#pragma unroll
    for (int p = 0; p < 4; ++p) {
        int k = r + p * 16;
        f32x4 v = *(const f32x4*)&in[(size_t)(kb + k) * N + nb + c4];
#pragma unroll
        for (int q = 0; q < 4; ++q) t[c4 + q][k] = f2bf(v[q]);
    }
    __syncthreads();
#pragma unroll
    for (int p = 0; p < 4; ++p) {
        int nn = r + p * 16;
        u16x4 o;
#pragma unroll
        for (int q = 0; q < 4; ++q) o[q] = t[nn][c4 + q];
        *(u16x4*)&out[(size_t)(nb + nn) * K + kb + c4] = o;
    }
}

// ---------------- GEMM1: qkv = x @ w_qkv + b, scatter to Q/K [BH][T][D], V^T [BH][D][T] ----------------

__global__ __launch_bounds__(256) void k_gemm_qkv(const u16* __restrict__ A,   // [8192][768]
                                                  const u16* __restrict__ BT,  // [2304][768]
                                                  const float* __restrict__ bias, // [2304]
                                                  u16* __restrict__ Qb,
                                                  u16* __restrict__ Kb,
                                                  u16* __restrict__ Vtg) {
    const int K = 768;
    __shared__ __align__(16) u16 As[128 * 32];
    __shared__ __align__(16) u16 Bs[128 * 32];
    const int tid = threadIdx.x;
    const int wave = tid >> 6, lane = tid & 63;
    const int wr = wave >> 1, wc = wave & 1;
    const int g = lane >> 4, lr = lane & 15;
    const int m0 = blockIdx.y * 128, n0 = blockIdx.x * 128;

    f32x4 acc[4][4];
#pragma unroll
    for (int i = 0; i < 4; ++i)
#pragma unroll
        for (int j = 0; j < 4; ++j) acc[i][j] = (f32x4){0.f, 0.f, 0.f, 0.f};

    for (int k0 = 0; k0 < K; k0 += 32) {
        __syncthreads();
#pragma unroll
        for (int it = 0; it < 2; ++it) {
            int c = tid + it * 256;
            int m = c >> 2, k8 = (c & 3) << 3;
            gl_lds16(&A[(size_t)(m0 + m) * K + k0 + k8], &As[c * 8]);
            gl_lds16(&BT[(size_t)(n0 + m) * K + k0 + k8], &Bs[c * 8]);
        }
        __syncthreads();
        short8 af[4], bf[4];
#pragma unroll
        for (int i = 0; i < 4; ++i)
            af[i] = *(const short8*)&As[(64 * wr + 16 * i + lr) * 32 + 8 * g];
#pragma unroll
        for (int j = 0; j < 4; ++j)
            bf[j] = *(const short8*)&Bs[(64 * wc + 16 * j + lr) * 32 + 8 * g];
#pragma unroll
        for (int i = 0; i < 4; ++i)
#pragma unroll
            for (int j = 0; j < 4; ++j)
                acc[i][j] = MFMA16(af[i], bf[j], acc[i][j]);
    }

#pragma unroll
    for (int i = 0; i < 4; ++i) {
        int row = m0 + 64 * wr + 16 * i + 4 * g;
#pragma unroll
        for (int j = 0; j < 4; ++j) {
            int col = n0 + 64 * wc + 16 * j + lr;
            int part = col / 768;
            int jj = col - part * 768;
            int h = jj / 96, d = jj - h * 96;
            float bsv = bias[col];
#pragma unroll
            for (int r = 0; r < 4; ++r) {
                int rw = row + r;
                int t = rw & 1023, bb = rw >> 10;
                int bh = bb * 8 + h;
                u16 val = f2bf(acc[i][j][r] + bsv);
                if (part == 0)      Qb[((size_t)bh * 1024 + t) * 96 + d] = val;
                else if (part == 1) Kb[((size_t)bh * 1024 + t) * 96 + d] = val;
                else                Vtg[((size_t)bh * 96 + d) * 1024 + t] = val;
            }
        }
    }
}

// ---------------- flash attention ----------------
// grid (8, 64): paired q-tiles (z, 15-z) for load balance; XCD-swizzled bh

__global__ __launch_bounds__(256) void k_attn(const u16* __restrict__ Qb,
                                              const u16* __restrict__ Kb,
                                              const u16* __restrict__ Vtg,
                                              u16* __restrict__ Yatt) {
    __shared__ __align__(16) u16 KsL[2][64 * 96];  // linear [t][d] (gload_lds dest)
    __shared__ __align__(16) u16 VtL[2][96 * 72];  // [d][t] pad 72
    __shared__ __align__(16) u16 Ps[4][16 * 72];   // per-wave P [16][64] pad 72

    const int tid = threadIdx.x;
    const int wave = tid >> 6, lane = tid & 63;
    const int g = lane >> 4, lr = lane & 15;

    // XCD-aware remap: each XCD gets 8 consecutive bh
    int id = blockIdx.y * 8 + blockIdx.x;
    int xcd = id & 7, slot = id >> 3;
    int nid = xcd * 64 + slot;
    int z = nid & 7, bh = nid >> 3;

    const size_t qkbase = (size_t)bh * 1024 * 96;  // Qb/Kb [t][96]
    const size_t vbase  = (size_t)bh * 96 * 1024;  // Vtg [d][1024]
    const float scale = 0.10206207261596577f; // 1/sqrt(96)
    const int b = bh >> 3, h = bh & 7;

    for (int seg = 0; seg < 2; ++seg) {
        const int qt = (seg == 0) ? z : 15 - z;
        const int q0 = qt * 64;

        short8 qf[3];
        {
            int qrow = q0 + 16 * wave + lr;
#pragma unroll
            for (int kk = 0; kk < 3; ++kk)
                qf[kk] = *(const short8*)&Qb[qkbase + (size_t)qrow * 96 + 32 * kk + 8 * g];
        }

        float m_r[4], l_r[4];
        f32x4 o[6];
#pragma unroll
        for (int r = 0; r < 4; ++r) { m_r[r] = -3e38f; l_r[r] = 0.f; }
#pragma unroll
        for (int c = 0; c < 6; ++c) o[c] = (f32x4){0.f, 0.f, 0.f, 0.f};

        u32x4 rv[3];
        // prologue: stage tile 0 into buf 0
#pragma unroll
        for (int it = 0; it < 3; ++it) {
            int c = tid + it * 256;
            gl_lds16(&Kb[qkbase + (size_t)(c / 12) * 96 + (c % 12) * 8], &KsL[0][c * 8]);
        }
#pragma unroll
        for (int it = 0; it < 3; ++it) {
            int c = tid + it * 256;
            rv[it] = *(const u32x4*)&Vtg[vbase + (size_t)(c >> 3) * 1024 + ((c & 7) << 3)];
        }
#pragma unroll
        for (int it = 0; it < 3; ++it) {
            int c = tid + it * 256;
            *(u32x4*)&VtL[0][(c >> 3) * 72 + ((c & 7) << 3)] = rv[it];
        }
        __syncthreads();

        for (int kt = 0; kt <= qt; ++kt) {
            const int cur = kt & 1;
            const bool pf = kt < qt;
            if (pf) {
                const int nk = (kt + 1) * 64;
#pragma unroll
                for (int it = 0; it < 3; ++it) {
                    int c = tid + it * 256;
                    gl_lds16(&Kb[qkbase + (size_t)(nk + c / 12) * 96 + (c % 12) * 8],
                             &KsL[cur ^ 1][c * 8]);
                }
#pragma unroll
                for (int it = 0; it < 3; ++it) {
                    int c = tid + it * 256;
                    rv[it] = *(const u32x4*)&Vtg[vbase + (size_t)(c >> 3) * 1024 + nk + ((c & 7) << 3)];
                }
            }

            // S = Q @ K^T : 16 rows x 64 cols per wave
            f32x4 s[4];
#pragma unroll
            for (int j = 0; j < 4; ++j) {
                s[j] = (f32x4){0.f, 0.f, 0.f, 0.f};
#pragma unroll
                for (int kk = 0; kk < 3; ++kk) {
                    short8 kf = *(const short8*)&KsL[cur][(16 * j + lr) * 96 + 32 * kk + 8 * g];
                    s[j] = MFMA16(qf[kk], kf, s[j]);
                }
            }
#pragma unroll
            for (int j = 0; j < 4; ++j)
#pragma unroll
                for (int r = 0; r < 4; ++r) s[j][r] *= scale;

            if (kt == qt) { // diagonal: mask local col > local row
#pragma unroll
                for (int j = 0; j < 4; ++j) {
                    int lc = 16 * j + lr;
#pragma unroll
                    for (int r = 0; r < 4; ++r) {
                        int lrow = 16 * wave + 4 * g + r;
                        if (lc > lrow) s[j][r] = -3e38f;
                    }
                }
            }

            // online softmax
            float alpha[4], rsum[4];
#pragma unroll
            for (int r = 0; r < 4; ++r) {
                float mx = fmaxf(fmaxf(s[0][r], s[1][r]), fmaxf(s[2][r], s[3][r]));
#pragma unroll
                for (int off = 1; off < 16; off <<= 1)
                    mx = fmaxf(mx, __shfl_xor(mx, off, 64));
                float mnew = fmaxf(m_r[r], mx);
                alpha[r] = __expf(m_r[r] - mnew);
                m_r[r] = mnew;
                rsum[r] = 0.f;
            }
#pragma unroll
            for (int j = 0; j < 4; ++j)
#pragma unroll
                for (int r = 0; r < 4; ++r) {
                    float p = __expf(s[j][r] - m_r[r]);
                    rsum[r] += p;
                    Ps[wave][(4 * g + r) * 72 + 16 * j + lr] = f2bf(p);
                }
#pragma unroll
            for (int r = 0; r < 4; ++r) {
#pragma unroll
                for (int off = 1; off < 16; off <<= 1)
                    rsum[r] += __shfl_xor(rsum[r], off, 64);
                l_r[r] = l_r[r] * alpha[r] + rsum[r];
            }
#pragma unroll
            for (int c = 0; c < 6; ++c)
#pragma unroll
                for (int r = 0; r < 4; ++r) o[c][r] *= alpha[r];

            // PV: o += P @ V
            short8 pfr[2];
#pragma unroll
            for (int kk = 0; kk < 2; ++kk)
                pfr[kk] = *(const short8*)&Ps[wave][lr * 72 + 32 * kk + 8 * g];
#pragma unroll
            for (int c = 0; c < 6; ++c) {
#pragma unroll
                for (int kk = 0; kk < 2; ++kk) {
                    short8 vf = *(const short8*)&VtL[cur][(16 * c + lr) * 72 + 32 * kk + 8 * g];
                    o[c] = MFMA16(pfr[kk], vf, o[c]);
                }
            }

            if (pf) { // write-late V staging into the other buffer
#pragma unroll
                for (int it = 0; it < 3; ++it) {
                    int c = tid + it * 256;
                    *(u32x4*)&VtL[cur ^ 1][(c >> 3) * 72 + ((c & 7) << 3)] = rv[it];
                }
            }
            __syncthreads();
        }

        // epilogue: Yatt[b][t][h*96+d]
#pragma unroll
        for (int r = 0; r < 4; ++r) {
            int t = q0 + 16 * wave + 4 * g + r;
            float inv = 1.0f / l_r[r];
            size_t rowoff = ((size_t)b * 1024 + t) * 768 + h * 96;
#pragma unroll
            for (int c = 0; c < 6; ++c)
                Yatt[rowoff + 16 * c + lr] = f2bf(o[c][r] * inv);
        }
        __syncthreads();
    }
}

// ---------------- GEMM2: out = yatt @ w_proj + b_proj (fp32 out) ----------------

__global__ __launch_bounds__(256) void k_gemm_out(const u16* __restrict__ A,   // [8192][768]
                                                  const u16* __restrict__ BT,  // [768][768]
                                                  const float* __restrict__ bias, // [768]
                                                  float* __restrict__ out) {   // [8192][768]
    const int K = 768;
    __shared__ __align__(16) u16 As[128 * 32];
    __shared__ __align__(16) u16 Bs[128 * 32];
    const int tid = threadIdx.x;
    const int wave = tid >> 6, lane = tid & 63;
    const int wr = wave >> 1, wc = wave & 1;
    const int g = lane >> 4, lr = lane & 15;
    const int m0 = blockIdx.y * 128, n0 = blockIdx.x * 128;

    f32x4 acc[4][4];
#pragma unroll
    for (int i = 0; i < 4; ++i)
#pragma unroll
        for (int j = 0; j < 4; ++j) acc[i][j] = (f32x4){0.f, 0.f, 0.f, 0.f};

    for (int k0 = 0; k0 < K; k0 += 32) {
        __syncthreads();
#pragma unroll
        for (int it = 0; it < 2; ++it) {
            int c = tid + it * 256;
            int m = c >> 2, k8 = (c & 3) << 3;
            gl_lds16(&A[(size_t)(m0 + m) * K + k0 + k8], &As[c * 8]);
            gl_lds16(&BT[(size_t)(n0 + m) * K + k0 + k8], &Bs[c * 8]);
        }
        __syncthreads();
        short8 af[4], bf[4];
#pragma unroll
        for (int i = 0; i < 4; ++i)
            af[i] = *(const short8*)&As[(64 * wr + 16 * i + lr) * 32 + 8 * g];
#pragma unroll
        for (int j = 0; j < 4; ++j)
            bf[j] = *(const short8*)&Bs[(64 * wc + 16 * j + lr) * 32 + 8 * g];
#pragma unroll
        for (int i = 0; i < 4; ++i)
#pragma unroll
            for (int j = 0; j < 4; ++j)
                acc[i][j] = MFMA16(af[i], bf[j], acc[i][j]);
    }

#pragma unroll
    for (int i = 0; i < 4; ++i) {
        int row = m0 + 64 * wr + 16 * i + 4 * g;
#pragma unroll
        for (int j = 0; j < 4; ++j) {
            int col = n0 + 64 * wc + 16 * j + lr;
            float bsv = bias[col];
#pragma unroll
            for (int r = 0; r < 4; ++r)
                out[(size_t)(row + r) * 768 + col] = acc[i][j][r] + bsv;
        }
    }
}

// ---------------- launch ----------------

extern "C" void kernel_launch(void* const* d_in, const int* in_sizes, int n_in,
                              void* d_out, int out_size, void* d_ws, size_t ws_size,
                              hipStream_t stream) {
    const float* x      = (const float*)d_in[0];
    const float* w_qkv  = (const float*)d_in[1];
    const float* b_qkv  = (const float*)d_in[2];
    const float* w_proj = (const float*)d_in[3];
    const float* b_proj = (const float*)d_in[4];
    float* out = (float*)d_out;

    u16* xb    = (u16*)d_ws;            // 6291456
    u16* wqkvT = xb + 6291456;          // 1769472
    u16* wpT   = wqkvT + 1769472;       // 589824
    u16* Qb    = wpT + 589824;          // 6291456
    u16* Kb    = Qb + 6291456;          // 6291456
    u16* Vtg   = Kb + 6291456;          // 6291456 ([bh][d][t])
    u16* Yatt  = Vtg + 6291456;         // 6291456

    k_cvt_x<<<6144, 256, 0, stream>>>(x, xb, 6291456);
    k_cvt_T<<<dim3(36, 12), 256, 0, stream>>>(w_qkv, wqkvT, 768, 2304);
    k_cvt_T<<<dim3(12, 12), 256, 0, stream>>>(w_proj, wpT, 768, 768);
    k_gemm_qkv<<<dim3(18, 64), 256, 0, stream>>>(xb, wqkvT, b_qkv, Qb, Kb, Vtg);
    k_attn<<<dim3(8, 64), 256, 0, stream>>>(Qb, Kb, Vtg, Yatt);
    k_gemm_out<<<dim3(6, 64), 256, 0, stream>>>(Yatt, wpT, b_proj, out);
}